// Round 1
// baseline (1376.729 us; speedup 1.0000x reference)
//
#include <hip/hip_runtime.h>
#include <hip/hip_bf16.h>
#include <cstddef>
#include <cstdint>

// ---------------------------------------------------------------------------
// StandardPartitionAttention — round 2: MFMA attention (wave per (w,h)) +
// LN fused into N=256 GEMM epilogues. bf16 activations, fp32 residual.
// ---------------------------------------------------------------------------

#define ROWS      65536
#define DMODEL    256
#define NWIN      1024
#define NHEADS    8
#define QKV_N     768
#define MLP_N     1024
#define SCALE_F   0.17677669529663687f
#define LN_EPS_F  1e-5f

typedef float f32x4 __attribute__((ext_vector_type(4)));
typedef __bf16 bf16x8 __attribute__((ext_vector_type(8)));

#define CP16(gp, lp)                                                          \
  __builtin_amdgcn_global_load_lds(                                           \
      (const __attribute__((address_space(1))) unsigned int*)(gp),            \
      (__attribute__((address_space(3))) unsigned int*)(lp), 16, 0, 0)

// ---------------- window gather: x[B,C,H,W] -> Xg[row, c] (bf16) ------------
__global__ __launch_bounds__(256) void gather_k(const float* __restrict__ x,
                                                __hip_bfloat16* __restrict__ Xg) {
  size_t idx = (size_t)blockIdx.x * 256 + threadIdx.x;
  int c   = (int)(idx & 255);
  int row = (int)(idx >> 8);
  int i   = row & 63;
  int wxy = row >> 6;
  int wx  = wxy & 15;
  int wy  = (wxy >> 4) & 15;
  int b   = wxy >> 8;
  int y   = wy * 8 + (i >> 3);
  int xx  = wx * 8 + (i & 7);
  Xg[idx] = __float2bfloat16(x[(((size_t)b * 256 + c) * 128 + y) * 128 + xx]);
}

// ---------------- un-window: t[row, d] -> out[B,D,H,W] ----------------------
__global__ __launch_bounds__(256) void unwindow_k(const float* __restrict__ t,
                                                  float* __restrict__ out) {
  size_t idx = (size_t)blockIdx.x * 256 + threadIdx.x;
  int xx = (int)(idx & 127);
  size_t r = idx >> 7;
  int y = (int)(r & 127); r >>= 7;
  int d = (int)(r & 255);
  int b = (int)(r >> 8);
  int row = ((b * 16 + (y >> 3)) * 16 + (xx >> 3)) * 64 + (y & 7) * 8 + (xx & 7);
  out[idx] = t[(size_t)row * DMODEL + d];
}

// ---------------- weight transpose + bf16 convert: [K,N] f32 -> [N,K] bf16 --
__global__ __launch_bounds__(256) void transpose_k(const float* __restrict__ src,
                                                   __hip_bfloat16* __restrict__ dst,
                                                   int K, int N) {
  __shared__ float tile[32][33];
  int tx = threadIdx.x, ty = threadIdx.y;
  int n0 = blockIdx.x * 32, k0 = blockIdx.y * 32;
#pragma unroll
  for (int i = 0; i < 4; ++i)
    tile[ty + i * 8][tx] = src[(size_t)(k0 + ty + i * 8) * N + n0 + tx];
  __syncthreads();
#pragma unroll
  for (int i = 0; i < 4; ++i)
    dst[(size_t)(n0 + ty + i * 8) * K + k0 + tx] =
        __float2bfloat16(tile[tx][ty + i * 8]);
}

// ---------------- bf16 MFMA GEMM (m97 structure, proven round 1) ------------
template <bool BIAS, bool RELU, bool RES, bool OBF16>
__global__ __launch_bounds__(256) void mm_k(const ushort* __restrict__ A,
                                            const ushort* __restrict__ BT,
                                            const float* __restrict__ bias,
                                            const float* __restrict__ res,
                                            void* __restrict__ Cout,
                                            int M, int N, int K) {
  __shared__ ushort As[4096];
  __shared__ ushort Bs[4096];
  const int tid = threadIdx.x;
  const int bm = blockIdx.y << 7, bn = blockIdx.x << 7;
  const ushort* Ap = A + (size_t)(bm + (tid >> 2)) * K + ((tid & 3) << 3);
  const ushort* Bp = BT + (size_t)(bn + (tid >> 2)) * K + ((tid & 3) << 3);
  const size_t k64 = (size_t)64 * K;
  const int lane = tid & 63, wave = tid >> 6;
  const int wm = (wave & 1) << 6, wn = (wave >> 1) << 6;
  const int lrow = lane & 15, kq = lane >> 4;
  const ushort* aF = &As[(wm + lrow) * 32 + kq * 8];
  const ushort* bF = &Bs[(wn + lrow) * 32 + kq * 8];
  f32x4 acc[4][4] = {};
  for (int k0 = 0; k0 < K; k0 += 32) {
    __syncthreads();
    CP16(Ap, &As[tid * 8]);
    CP16(Ap + k64, &As[2048 + tid * 8]);
    CP16(Bp, &Bs[tid * 8]);
    CP16(Bp + k64, &Bs[2048 + tid * 8]);
    Ap += 32; Bp += 32;
    __syncthreads();
    bf16x8 af[4], bf[4];
#pragma unroll
    for (int i = 0; i < 4; ++i) af[i] = *(const bf16x8*)(aF + i * 512);
#pragma unroll
    for (int j = 0; j < 4; ++j) bf[j] = *(const bf16x8*)(bF + j * 512);
#pragma unroll
    for (int i = 0; i < 4; ++i)
#pragma unroll
      for (int j = 0; j < 4; ++j)
        acc[i][j] =
            __builtin_amdgcn_mfma_f32_16x16x32_bf16(af[i], bf[j], acc[i][j], 0, 0, 0);
  }
  const int r0 = bm + wm + kq * 4;
  const int c0 = bn + wn + lrow;
#pragma unroll
  for (int i = 0; i < 4; ++i) {
#pragma unroll
    for (int j = 0; j < 4; ++j) {
      const int col = c0 + j * 16;
      const float bv = BIAS ? bias[col] : 0.f;
#pragma unroll
      for (int r = 0; r < 4; ++r) {
        const int row = r0 + i * 16 + r;
        float v = acc[i][j][r] + bv;
        if (RELU) v = fmaxf(v, 0.f);
        if (RES) v += res[(size_t)row * N + col];
        if (OBF16)
          ((__hip_bfloat16*)Cout)[(size_t)row * N + col] = __float2bfloat16(v);
        else
          ((float*)Cout)[(size_t)row * N + col] = v;
      }
    }
  }
}

// ---------------- GEMM (N=256, tile 64x256) + fused LayerNorm ---------------
// Writes Tout (f32 residual stream) and Hout (bf16 LN output).
template <bool RES>
__global__ __launch_bounds__(256) void mm_ln_k(const ushort* __restrict__ A,
                                               const ushort* __restrict__ BT,
                                               const float* __restrict__ bias,
                                               const float* __restrict__ res,
                                               float* __restrict__ Tout,
                                               __hip_bfloat16* __restrict__ Hout,
                                               const float* __restrict__ g,
                                               const float* __restrict__ bb,
                                               int K) {
  __shared__ ushort As[2048];      // 64 x 32
  __shared__ ushort Bs[8192];      // 256 x 32
  __shared__ float rs[64][4], rs2[64][4];
  const int tid = threadIdx.x;
  const int bm = blockIdx.x << 6;
  const ushort* Ap = A + (size_t)(bm + (tid >> 2)) * K + ((tid & 3) << 3);
  const ushort* Bp = BT + (size_t)(tid >> 2) * K + ((tid & 3) << 3);
  const size_t k64 = (size_t)64 * K;
  const int lane = tid & 63, wave = tid >> 6;
  const int l15 = lane & 15, quad = lane >> 4;
  const ushort* aF = &As[l15 * 32 + quad * 8];
  const ushort* bF = &Bs[(wave * 64 + l15) * 32 + quad * 8];
  f32x4 acc[4][4] = {};
  for (int k0 = 0; k0 < K; k0 += 32) {
    __syncthreads();
    CP16(Ap, &As[tid * 8]);
    CP16(Bp, &Bs[tid * 8]);
    CP16(Bp + k64, &Bs[2048 + tid * 8]);
    CP16(Bp + 2 * k64, &Bs[4096 + tid * 8]);
    CP16(Bp + 3 * k64, &Bs[6144 + tid * 8]);
    Ap += 32; Bp += 32;
    __syncthreads();
    bf16x8 af[4], bf[4];
#pragma unroll
    for (int i = 0; i < 4; ++i) af[i] = *(const bf16x8*)(aF + i * 512);
#pragma unroll
    for (int j = 0; j < 4; ++j) bf[j] = *(const bf16x8*)(bF + j * 512);
#pragma unroll
    for (int i = 0; i < 4; ++i)
#pragma unroll
      for (int j = 0; j < 4; ++j)
        acc[i][j] =
            __builtin_amdgcn_mfma_f32_16x16x32_bf16(af[i], bf[j], acc[i][j], 0, 0, 0);
  }
  // epilogue: bias (+res), then full-row LN across 256 cols
  const int rb = quad * 4;
#pragma unroll
  for (int i = 0; i < 4; ++i)
#pragma unroll
    for (int j = 0; j < 4; ++j) {
      const int col = wave * 64 + j * 16 + l15;
      const float bv = bias[col];
#pragma unroll
      for (int r = 0; r < 4; ++r) {
        const int row = bm + i * 16 + rb + r;
        float x = acc[i][j][r] + bv;
        if (RES) x += res[(size_t)row * 256 + col];
        acc[i][j][r] = x;
      }
    }
#pragma unroll
  for (int i = 0; i < 4; ++i)
#pragma unroll
    for (int r = 0; r < 4; ++r) {
      float s = 0.f, s2 = 0.f;
#pragma unroll
      for (int j = 0; j < 4; ++j) {
        float x = acc[i][j][r];
        s += x; s2 += x * x;
      }
      s += __shfl_xor(s, 1);  s += __shfl_xor(s, 2);
      s += __shfl_xor(s, 4);  s += __shfl_xor(s, 8);
      s2 += __shfl_xor(s2, 1); s2 += __shfl_xor(s2, 2);
      s2 += __shfl_xor(s2, 4); s2 += __shfl_xor(s2, 8);
      if (l15 == 0) {
        rs[i * 16 + rb + r][wave] = s;
        rs2[i * 16 + rb + r][wave] = s2;
      }
    }
  __syncthreads();
  float mrow[4][4], rrow[4][4];
#pragma unroll
  for (int i = 0; i < 4; ++i)
#pragma unroll
    for (int r = 0; r < 4; ++r) {
      const int lr = i * 16 + rb + r;
      float4 s4 = *(const float4*)rs[lr];
      float4 q4 = *(const float4*)rs2[lr];
      float tot = s4.x + s4.y + s4.z + s4.w;
      float tot2 = q4.x + q4.y + q4.z + q4.w;
      float m = tot * (1.0f / 256.0f);
      float var = tot2 * (1.0f / 256.0f) - m * m;
      mrow[i][r] = m;
      rrow[i][r] = rsqrtf(var + LN_EPS_F);
    }
#pragma unroll
  for (int i = 0; i < 4; ++i)
#pragma unroll
    for (int j = 0; j < 4; ++j) {
      const int col = wave * 64 + j * 16 + l15;
      const float gv = g[col], bv = bb[col];
#pragma unroll
      for (int r = 0; r < 4; ++r) {
        const int row = bm + i * 16 + rb + r;
        float x = acc[i][j][r];
        Tout[(size_t)row * 256 + col] = x;
        Hout[(size_t)row * 256 + col] =
            __float2bfloat16((x - mrow[i][r]) * rrow[i][r] * gv + bv);
      }
    }
}

// ---------------- attention v3: MFMA, one wave per (window, head) -----------
// Block = 4 waves = 4 windows, one head (shared bias+pos table). No barriers
// after staging. q/k row-major (A / B^T layouts for QK^T); V staged transposed.
__global__ __launch_bounds__(256) void attn_k(const ushort* __restrict__ qkv,
                                              __hip_bfloat16* __restrict__ o,
                                              float* __restrict__ attns_out,
                                              const float* __restrict__ bias_tbl,
                                              const float* __restrict__ sita_l) {
  // per-wave region: q 64x40 (2560), k 64x40 (2560), vT 32x72 (2304) = 7424 ush
  __shared__ ushort smem[4 * 7424];
  __shared__ float tbl[225];
  const int tid = threadIdx.x;
  const int lane = tid & 63, wave = tid >> 6;
  const int head = blockIdx.x & 7;
  const int w = ((blockIdx.x >> 3) << 2) + wave;
  ushort* qw = smem + wave * 7424;
  ushort* kw = qw + 2560;
  ushort* vw = kw + 2560;
  ushort* Pw = qw;                 // 64x72 = 4608 <= 5120 (q+k dead after QK)

  const float sita = sita_l[head];
  const float factor = 1.0f / (2.0f * sita * sita + 1e-10f);
  for (int idx = tid; idx < 225; idx += 256) {
    int dyi = idx / 15 - 7, dxi = idx % 15 - 7;
    float dis = (float)(dyi * dyi + dxi * dxi) * 0.015625f;
    tbl[idx] = bias_tbl[idx * NHEADS + head] + 0.01f * __expf(-factor * dis);
  }

  // stage q,k row-major [tok][d]; v transposed [d][tok]
  {
    const ushort* base = qkv + (size_t)(w * 64) * QKV_N + head * 32;
    const int r0 = lane >> 2, c = (lane & 3) << 3;
#pragma unroll
    for (int r4 = 0; r4 < 4; ++r4) {
      const int row = r4 * 16 + r0;
      const ushort* rp = base + (size_t)row * QKV_N + c;
      *(uint4*)(qw + row * 40 + c) = *(const uint4*)(rp);
      *(uint4*)(kw + row * 40 + c) = *(const uint4*)(rp + 256);
      union { uint4 u; ushort s[8]; } V;
      V.u = *(const uint4*)(rp + 512);
#pragma unroll
      for (int z = 0; z < 8; ++z) vw[(c + z) * 72 + row] = V.s[z];
    }
  }
  __syncthreads();

  const int l15 = lane & 15, quad = lane >> 4;

  // QK^T: 16 MFMA, C-layout acc
  f32x4 acc[4][4] = {};
  {
    bf16x8 af[4], bfr[4];
#pragma unroll
    for (int i = 0; i < 4; ++i)
      af[i] = *(const bf16x8*)(qw + (i * 16 + l15) * 40 + quad * 8);
#pragma unroll
    for (int j = 0; j < 4; ++j)
      bfr[j] = *(const bf16x8*)(kw + (j * 16 + l15) * 40 + quad * 8);
#pragma unroll
    for (int i = 0; i < 4; ++i)
#pragma unroll
      for (int j = 0; j < 4; ++j)
        acc[i][j] =
            __builtin_amdgcn_mfma_f32_16x16x32_bf16(af[i], bfr[j], acc[i][j], 0, 0, 0);
  }

  // scores: acc <- dots0 (scaled); e1 <- dots0 + bias + 0.01*pos
  float e1[4][4][4];
#pragma unroll
  for (int i = 0; i < 4; ++i)
#pragma unroll
    for (int r = 0; r < 4; ++r) {
      const int row = i * 16 + quad * 4 + r;
      const int iy = row >> 3, ix = row & 7;
#pragma unroll
      for (int j = 0; j < 4; ++j) {
        const int col = j * 16 + l15;
        const int jy = col >> 3, jx = col & 7;
        float d0 = acc[i][j][r] * SCALE_F;
        acc[i][j][r] = d0;
        e1[i][j][r] = d0 + tbl[(iy - jy + 7) * 15 + (ix - jx + 7)];
      }
    }

  // dual softmax per row (lane-group of 16 holds a row across 4 j-tiles)
#pragma unroll
  for (int i = 0; i < 4; ++i)
#pragma unroll
    for (int r = 0; r < 4; ++r) {
      float m0 = -1e30f, m1 = -1e30f;
#pragma unroll
      for (int j = 0; j < 4; ++j) {
        m0 = fmaxf(m0, acc[i][j][r]);
        m1 = fmaxf(m1, e1[i][j][r]);
      }
      m0 = fmaxf(m0, __shfl_xor(m0, 1)); m0 = fmaxf(m0, __shfl_xor(m0, 2));
      m0 = fmaxf(m0, __shfl_xor(m0, 4)); m0 = fmaxf(m0, __shfl_xor(m0, 8));
      m1 = fmaxf(m1, __shfl_xor(m1, 1)); m1 = fmaxf(m1, __shfl_xor(m1, 2));
      m1 = fmaxf(m1, __shfl_xor(m1, 4)); m1 = fmaxf(m1, __shfl_xor(m1, 8));
      float z0 = 0.f, z1 = 0.f;
#pragma unroll
      for (int j = 0; j < 4; ++j) {
        float a = __expf(acc[i][j][r] - m0); acc[i][j][r] = a; z0 += a;
        float bqq = __expf(e1[i][j][r] - m1); e1[i][j][r] = bqq; z1 += bqq;
      }
      z0 += __shfl_xor(z0, 1); z0 += __shfl_xor(z0, 2);
      z0 += __shfl_xor(z0, 4); z0 += __shfl_xor(z0, 8);
      z1 += __shfl_xor(z1, 1); z1 += __shfl_xor(z1, 2);
      z1 += __shfl_xor(z1, 4); z1 += __shfl_xor(z1, 8);
      const float r0i = 1.f / z0, r1i = 1.f / z1;
#pragma unroll
      for (int j = 0; j < 4; ++j) {
        acc[i][j][r] *= r0i;
        e1[i][j][r] *= r1i;
      }
    }

  // write attns (softmax of dots0) to d_out
  {
    float* ab = attns_out + ((size_t)(w * NHEADS + head)) * 4096;
#pragma unroll
    for (int i = 0; i < 4; ++i)
#pragma unroll
      for (int j = 0; j < 4; ++j)
#pragma unroll
        for (int r = 0; r < 4; ++r)
          ab[(i * 16 + quad * 4 + r) * 64 + j * 16 + l15] = acc[i][j][r];
  }

  // P (biased softmax) -> LDS row-major bf16 (A-operand layout for AV)
#pragma unroll
  for (int i = 0; i < 4; ++i)
#pragma unroll
    for (int j = 0; j < 4; ++j)
#pragma unroll
      for (int r = 0; r < 4; ++r)
        Pw[(i * 16 + quad * 4 + r) * 72 + j * 16 + l15] =
            ((__hip_bfloat16_raw)__float2bfloat16(e1[i][j][r])).x;

  // AV: O = P @ V  (M=64, N=32, K=64 -> 16 MFMA)
  f32x4 oacc[4][2] = {};
#pragma unroll
  for (int ks = 0; ks < 2; ++ks) {
    bf16x8 pa[4], vb[2];
#pragma unroll
    for (int i = 0; i < 4; ++i)
      pa[i] = *(const bf16x8*)(Pw + (i * 16 + l15) * 72 + ks * 32 + quad * 8);
#pragma unroll
    for (int j = 0; j < 2; ++j)
      vb[j] = *(const bf16x8*)(vw + (j * 16 + l15) * 72 + ks * 32 + quad * 8);
#pragma unroll
    for (int i = 0; i < 4; ++i)
#pragma unroll
      for (int j = 0; j < 2; ++j)
        oacc[i][j] =
            __builtin_amdgcn_mfma_f32_16x16x32_bf16(pa[i], vb[j], oacc[i][j], 0, 0, 0);
  }
  {
    ushort* ob = (ushort*)o + (size_t)(w * 64) * DMODEL + head * 32;
#pragma unroll
    for (int i = 0; i < 4; ++i)
#pragma unroll
      for (int j = 0; j < 2; ++j)
#pragma unroll
        for (int r = 0; r < 4; ++r)
          ob[(size_t)(i * 16 + quad * 4 + r) * DMODEL + j * 16 + l15] =
              ((__hip_bfloat16_raw)__float2bfloat16(oacc[i][j][r])).x;
  }
}

// ---------------------------------------------------------------------------
extern "C" void kernel_launch(void* const* d_in, const int* in_sizes, int n_in,
                              void* d_out, int out_size, void* d_ws, size_t ws_size,
                              hipStream_t stream) {
  const float* x        = (const float*)d_in[0];
  const float* W_patch  = (const float*)d_in[1];
  const float* b_patch  = (const float*)d_in[2];
  const float* ln1_g    = (const float*)d_in[3];
  const float* ln1_b    = (const float*)d_in[4];
  const float* Wqkv     = (const float*)d_in[5];
  const float* headsita = (const float*)d_in[6];
  const float* bias_tbl = (const float*)d_in[7];
  const float* Wout     = (const float*)d_in[8];
  const float* bout     = (const float*)d_in[9];
  const float* ln2_g    = (const float*)d_in[10];
  const float* ln2_b    = (const float*)d_in[11];
  const float* W1       = (const float*)d_in[12];
  const float* b1       = (const float*)d_in[13];
  const float* W2       = (const float*)d_in[14];
  const float* b2       = (const float*)d_in[15];

  char* W = (char*)d_ws;
  float*  t   = (float*)W;                       // [65536,256] f32, 64 MB
  ushort* h   = (ushort*)(W + 67108864);         // [65536,256] bf16, 32 MB
  ushort* qkv = (ushort*)(W + 100663296);        // [65536,768] bf16, 96 MB
  ushort* o   = (ushort*)(W + 201326592);        // [65536,256] bf16, 32 MB
  ushort* wT  = (ushort*)(W + 234881024);        // transposed bf16 weights
  ushort* Xg  = qkv;                             // overlap (dead before qkv GEMM)
  ushort* hid = qkv;                             // [65536,1024] bf16

  ushort* WpT   = wT;
  ushort* WqkvT = wT + 65536;
  ushort* WoutT = wT + 458752;
  ushort* W1T   = wT + 589824;
  ushort* W2T   = wT + 1114112;

  float* out_img = (float*)d_out;
  float* attns   = out_img + 16777216;

  const dim3 tb(32, 8);
  transpose_k<<<dim3(8, 8),  tb, 0, stream>>>(W_patch, (__hip_bfloat16*)WpT, 256, 256);
  for (int l = 0; l < 2; ++l) {
    transpose_k<<<dim3(24, 8), tb, 0, stream>>>(Wqkv + (size_t)l * 196608,
        (__hip_bfloat16*)(WqkvT + (size_t)l * 196608), 256, 768);
    transpose_k<<<dim3(8, 8),  tb, 0, stream>>>(Wout + (size_t)l * 65536,
        (__hip_bfloat16*)(WoutT + (size_t)l * 65536), 256, 256);
    transpose_k<<<dim3(32, 8), tb, 0, stream>>>(W1 + (size_t)l * 262144,
        (__hip_bfloat16*)(W1T + (size_t)l * 262144), 256, 1024);
    transpose_k<<<dim3(8, 32), tb, 0, stream>>>(W2 + (size_t)l * 262144,
        (__hip_bfloat16*)(W2T + (size_t)l * 262144), 1024, 256);
  }

  gather_k<<<65536, 256, 0, stream>>>(x, (__hip_bfloat16*)Xg);
  // patch embed + fused LN1 (layer 0)
  mm_ln_k<false><<<1024, 256, 0, stream>>>(
      Xg, WpT, b_patch, nullptr, t, (__hip_bfloat16*)h, ln1_g, ln1_b, 256);

  for (int l = 0; l < 2; ++l) {
    mm_k<false, false, false, true><<<dim3(6, 512), 256, 0, stream>>>(
        h, WqkvT + (size_t)l * 196608, nullptr, nullptr, qkv, ROWS, QKV_N, DMODEL);
    attn_k<<<2048, 256, 0, stream>>>(
        qkv, (__hip_bfloat16*)o, attns + (size_t)l * 33554432,
        bias_tbl + l * 225 * NHEADS, headsita + l * NHEADS);
    // out-proj + residual + fused LN2
    mm_ln_k<true><<<1024, 256, 0, stream>>>(
        o, WoutT + (size_t)l * 65536, bout + l * 256, t, t, (__hip_bfloat16*)h,
        ln2_g + l * 256, ln2_b + l * 256, 256);
    mm_k<true, true, false, true><<<dim3(8, 512), 256, 0, stream>>>(
        h, W1T + (size_t)l * 262144, b1 + l * MLP_N, nullptr, hid, ROWS, MLP_N, DMODEL);
    if (l == 0) {
      // W2 + residual + fused LN1 of layer 1
      mm_ln_k<true><<<1024, 256, 0, stream>>>(
          hid, W2T, b2, t, t, (__hip_bfloat16*)h, ln1_g + 256, ln1_b + 256, 1024);
    } else {
      mm_k<true, false, true, false><<<dim3(2, 512), 256, 0, stream>>>(
          hid, W2T + 262144, b2 + 256, t, t, ROWS, DMODEL, MLP_N);
    }
  }

  unwindow_k<<<65536, 256, 0, stream>>>(t, out_img);
}

// Round 2
// 1166.504 us; speedup vs baseline: 1.1802x; 1.1802x over previous
//
#include <hip/hip_runtime.h>
#include <hip/hip_bf16.h>
#include <cstddef>
#include <cstdint>

// ---------------------------------------------------------------------------
// StandardPartitionAttention — round 3:
//  * mm_k / mm_ln_k: BK=64 (half the barrier drains per FLOP), proven [*][32]
//    LDS sub-tile geometry kept.
//  * mm_k grid swapped: M-tiles fastest -> each A-panel fetched once.
//  * gather/unwindow: LDS-transpose, coalesced both sides.
//  * 11 weight-transpose launches merged into 1.
// ---------------------------------------------------------------------------

#define ROWS      65536
#define DMODEL    256
#define NWIN      1024
#define NHEADS    8
#define QKV_N     768
#define MLP_N     1024
#define SCALE_F   0.17677669529663687f
#define LN_EPS_F  1e-5f

typedef float f32x4 __attribute__((ext_vector_type(4)));
typedef __bf16 bf16x8 __attribute__((ext_vector_type(8)));

#define CP16(gp, lp)                                                          \
  __builtin_amdgcn_global_load_lds(                                           \
      (const __attribute__((address_space(1))) unsigned int*)(gp),            \
      (__attribute__((address_space(3))) unsigned int*)(lp), 16, 0, 0)

// ---------------- window gather: x[B,C,H,W] -> Xg[row, c] (bf16) ------------
// block = (b, y, c-chunk of 64). Coalesced float4 reads, LDS transpose,
// 64B-contiguous bf16 writes.
__global__ __launch_bounds__(256) void gather_k(const float* __restrict__ x,
                                                ushort* __restrict__ Xg) {
  __shared__ float tile[64 * 132];   // [c'][xx], pad 132 (16B-aligned rows)
  const int tid = threadIdx.x;
  const int bid = blockIdx.x;
  const int chunk = bid & 3;
  const int y = (bid >> 2) & 127;
  const int b = bid >> 9;
  const int c0 = chunk << 6;
  // read: 8 passes, 8 c-rows each; 512B contiguous per row
  {
    const int x4 = tid & 31, cr = tid >> 5;
#pragma unroll
    for (int p = 0; p < 8; ++p) {
      const int cl = cr + p * 8;
      const float4 v = *(const float4*)(x +
          ((((size_t)b * 256 + c0 + cl) * 128 + y) * 128 + x4 * 4));
      *(float4*)(tile + cl * 132 + x4 * 4) = v;
    }
  }
  __syncthreads();
  // write: thread = (xx, half of c-chunk); 64B contiguous per thread
  {
    const int xx = tid >> 1, half = tid & 1;
    union { ushort s[32]; uint4 q[4]; } U;
#pragma unroll
    for (int cp = 0; cp < 32; ++cp) {
      const float v = tile[(half * 32 + cp) * 132 + xx];
      U.s[cp] = ((__hip_bfloat16_raw)__float2bfloat16(v)).x;
    }
    const int row = ((b * 16 + (y >> 3)) * 16 + (xx >> 3)) * 64 +
                    (y & 7) * 8 + (xx & 7);
    uint4* dst = (uint4*)(Xg + (size_t)row * 256 + c0 + half * 32);
#pragma unroll
    for (int z = 0; z < 4; ++z) dst[z] = U.q[z];
  }
}

// ---------------- un-window: t[row, d] -> out[B,D,H,W] ----------------------
// block = (b, y, d-chunk of 64). Coalesced float4 reads of t rows, LDS
// transpose, coalesced f32 writes along xx.
__global__ __launch_bounds__(256) void unwindow_k(const float* __restrict__ t,
                                                  float* __restrict__ out) {
  __shared__ float tile[128 * 65];   // [xx][d'], pad 65
  const int tid = threadIdx.x;
  const int bid = blockIdx.x;
  const int dchunk = bid & 3;
  const int y = (bid >> 2) & 127;
  const int b = bid >> 9;
  const int d0 = dchunk << 6;
  {
    const int d4 = tid & 15, xr = tid >> 4;
#pragma unroll
    for (int p = 0; p < 8; ++p) {
      const int xx = xr + p * 16;
      const int row = ((b * 16 + (y >> 3)) * 16 + (xx >> 3)) * 64 +
                      (y & 7) * 8 + (xx & 7);
      const float4 v = *(const float4*)(t + (size_t)row * 256 + d0 + d4 * 4);
      tile[xx * 65 + d4 * 4 + 0] = v.x;
      tile[xx * 65 + d4 * 4 + 1] = v.y;
      tile[xx * 65 + d4 * 4 + 2] = v.z;
      tile[xx * 65 + d4 * 4 + 3] = v.w;
    }
  }
  __syncthreads();
  {
    const int xx = tid & 127, dd = tid >> 7;
#pragma unroll
    for (int p = 0; p < 32; ++p) {
      const int d = p * 2 + dd;
      out[(((size_t)b * 256 + d0 + d) * 128 + y) * 128 + xx] =
          tile[xx * 65 + d];
    }
  }
}

// ---------------- all weight transposes in one launch -----------------------
__global__ __launch_bounds__(256) void transpose_all_k(
    const float* __restrict__ Wp, const float* __restrict__ Wqkv,
    const float* __restrict__ Wo, const float* __restrict__ W1,
    const float* __restrict__ W2, ushort* __restrict__ WpT,
    ushort* __restrict__ WqkvT, ushort* __restrict__ WoT,
    ushort* __restrict__ W1T, ushort* __restrict__ W2T) {
  __shared__ float tile[32][33];
  const int bid = blockIdx.x;
  const float* src; ushort* dst; int K, N, r;
  if (bid < 64) { src = Wp; dst = WpT; K = 256; N = 256; r = bid; }
  else {
    const int tt = bid - 64, l = tt / 768; r = tt % 768;
    if (r < 192)      { src = Wqkv + (size_t)l * 196608; dst = WqkvT + (size_t)l * 196608; K = 256; N = 768; }
    else if (r < 256) { src = Wo + (size_t)l * 65536;  dst = WoT + (size_t)l * 65536;  K = 256; N = 256;  r -= 192; }
    else if (r < 512) { src = W1 + (size_t)l * 262144; dst = W1T + (size_t)l * 262144; K = 256; N = 1024; r -= 256; }
    else              { src = W2 + (size_t)l * 262144; dst = W2T + (size_t)l * 262144; K = 1024; N = 256; r -= 512; }
  }
  const int nx = N >> 5;
  const int n0 = (r % nx) * 32, k0 = (r / nx) * 32;
  const int tx = threadIdx.x & 31, ty = threadIdx.x >> 5;
#pragma unroll
  for (int i = 0; i < 4; ++i)
    tile[ty + i * 8][tx] = src[(size_t)(k0 + ty + i * 8) * N + n0 + tx];
  __syncthreads();
#pragma unroll
  for (int i = 0; i < 4; ++i)
    dst[(size_t)(n0 + ty + i * 8) * K + k0 + tx] =
        ((__hip_bfloat16_raw)__float2bfloat16(tile[tx][ty + i * 8])).x;
}

// ---------------- bf16 MFMA GEMM, 128x128 tile, BK=64 -----------------------
// LDS: As/Bs = [2 k-chunks][128 rows][32 cols] (proven m97 stride kept).
// Grid: (M-tiles, N-tiles) with M fastest -> A-panels fetched once.
template <bool BIAS, bool RELU, bool RES, bool OBF16>
__global__ __launch_bounds__(256) void mm_k(const ushort* __restrict__ A,
                                            const ushort* __restrict__ BT,
                                            const float* __restrict__ bias,
                                            const float* __restrict__ res,
                                            void* __restrict__ Cout,
                                            int M, int N, int K) {
  __shared__ ushort As[8192];
  __shared__ ushort Bs[8192];
  const int tid = threadIdx.x;
  const int bm = blockIdx.x << 7, bn = blockIdx.y << 7;
  const ushort* Ap = A + (size_t)(bm + (tid >> 2)) * K + ((tid & 3) << 3);
  const ushort* Bp = BT + (size_t)(bn + (tid >> 2)) * K + ((tid & 3) << 3);
  const size_t k64 = (size_t)64 * K;
  const int lane = tid & 63, wave = tid >> 6;
  const int wm = (wave & 1) << 6, wn = (wave >> 1) << 6;
  const int lrow = lane & 15, kq = lane >> 4;
  const ushort* aF = &As[(wm + lrow) * 32 + kq * 8];
  const ushort* bF = &Bs[(wn + lrow) * 32 + kq * 8];
  f32x4 acc[4][4] = {};
  for (int k0 = 0; k0 < K; k0 += 64) {
    __syncthreads();
    CP16(Ap, &As[tid * 8]);
    CP16(Ap + k64, &As[2048 + tid * 8]);
    CP16(Ap + 32, &As[4096 + tid * 8]);
    CP16(Ap + k64 + 32, &As[6144 + tid * 8]);
    CP16(Bp, &Bs[tid * 8]);
    CP16(Bp + k64, &Bs[2048 + tid * 8]);
    CP16(Bp + 32, &Bs[4096 + tid * 8]);
    CP16(Bp + k64 + 32, &Bs[6144 + tid * 8]);
    Ap += 64; Bp += 64;
    __syncthreads();
#pragma unroll
    for (int c = 0; c < 2; ++c) {
      bf16x8 af[4], bf[4];
#pragma unroll
      for (int i = 0; i < 4; ++i) af[i] = *(const bf16x8*)(aF + c * 4096 + i * 512);
#pragma unroll
      for (int j = 0; j < 4; ++j) bf[j] = *(const bf16x8*)(bF + c * 4096 + j * 512);
#pragma unroll
      for (int i = 0; i < 4; ++i)
#pragma unroll
        for (int j = 0; j < 4; ++j)
          acc[i][j] =
              __builtin_amdgcn_mfma_f32_16x16x32_bf16(af[i], bf[j], acc[i][j], 0, 0, 0);
    }
  }
  const int r0 = bm + wm + kq * 4;
  const int c0 = bn + wn + lrow;
#pragma unroll
  for (int i = 0; i < 4; ++i) {
#pragma unroll
    for (int j = 0; j < 4; ++j) {
      const int col = c0 + j * 16;
      const float bv = BIAS ? bias[col] : 0.f;
#pragma unroll
      for (int r = 0; r < 4; ++r) {
        const int row = r0 + i * 16 + r;
        float v = acc[i][j][r] + bv;
        if (RELU) v = fmaxf(v, 0.f);
        if (RES) v += res[(size_t)row * N + col];
        if (OBF16)
          ((__hip_bfloat16*)Cout)[(size_t)row * N + col] = __float2bfloat16(v);
        else
          ((float*)Cout)[(size_t)row * N + col] = v;
      }
    }
  }
}

// ---------------- GEMM (N=256, tile 64x256, BK=64) + fused LayerNorm --------
template <bool RES>
__global__ __launch_bounds__(256) void mm_ln_k(const ushort* __restrict__ A,
                                               const ushort* __restrict__ BT,
                                               const float* __restrict__ bias,
                                               const float* __restrict__ res,
                                               float* __restrict__ Tout,
                                               __hip_bfloat16* __restrict__ Hout,
                                               const float* __restrict__ g,
                                               const float* __restrict__ bb,
                                               int K) {
  __shared__ ushort As[4096];       // [2][64][32]
  __shared__ ushort Bs[16384];      // [2][256][32]
  __shared__ float rs[64][4], rs2[64][4];
  const int tid = threadIdx.x;
  const int bm = blockIdx.x << 6;
  const ushort* Ap = A + (size_t)(bm + (tid >> 2)) * K + ((tid & 3) << 3);
  const ushort* Bp = BT + (size_t)(tid >> 2) * K + ((tid & 3) << 3);
  const size_t k64 = (size_t)64 * K;
  const int lane = tid & 63, wave = tid >> 6;
  const int l15 = lane & 15, quad = lane >> 4;
  const ushort* aF = &As[l15 * 32 + quad * 8];
  const ushort* bF = &Bs[(wave * 64 + l15) * 32 + quad * 8];
  f32x4 acc[4][4] = {};
  for (int k0 = 0; k0 < K; k0 += 64) {
    __syncthreads();
    CP16(Ap, &As[tid * 8]);
    CP16(Ap + 32, &As[2048 + tid * 8]);
#pragma unroll
    for (int cb = 0; cb < 4; ++cb) {
      CP16(Bp + cb * k64, &Bs[cb * 2048 + tid * 8]);
      CP16(Bp + cb * k64 + 32, &Bs[8192 + cb * 2048 + tid * 8]);
    }
    Ap += 64; Bp += 64;
    __syncthreads();
#pragma unroll
    for (int c = 0; c < 2; ++c) {
      bf16x8 af[4], bf[4];
#pragma unroll
      for (int i = 0; i < 4; ++i) af[i] = *(const bf16x8*)(aF + c * 2048 + i * 512);
#pragma unroll
      for (int j = 0; j < 4; ++j) bf[j] = *(const bf16x8*)(bF + c * 8192 + j * 512);
#pragma unroll
      for (int i = 0; i < 4; ++i)
#pragma unroll
        for (int j = 0; j < 4; ++j)
          acc[i][j] =
              __builtin_amdgcn_mfma_f32_16x16x32_bf16(af[i], bf[j], acc[i][j], 0, 0, 0);
    }
  }
  // epilogue: bias (+res), then full-row LN across 256 cols
  const int rb = quad * 4;
#pragma unroll
  for (int i = 0; i < 4; ++i)
#pragma unroll
    for (int j = 0; j < 4; ++j) {
      const int col = wave * 64 + j * 16 + l15;
      const float bv = bias[col];
#pragma unroll
      for (int r = 0; r < 4; ++r) {
        const int row = bm + i * 16 + rb + r;
        float x = acc[i][j][r] + bv;
        if (RES) x += res[(size_t)row * 256 + col];
        acc[i][j][r] = x;
      }
    }
#pragma unroll
  for (int i = 0; i < 4; ++i)
#pragma unroll
    for (int r = 0; r < 4; ++r) {
      float s = 0.f, s2 = 0.f;
#pragma unroll
      for (int j = 0; j < 4; ++j) {
        float x = acc[i][j][r];
        s += x; s2 += x * x;
      }
      s += __shfl_xor(s, 1);  s += __shfl_xor(s, 2);
      s += __shfl_xor(s, 4);  s += __shfl_xor(s, 8);
      s2 += __shfl_xor(s2, 1); s2 += __shfl_xor(s2, 2);
      s2 += __shfl_xor(s2, 4); s2 += __shfl_xor(s2, 8);
      if (l15 == 0) {
        rs[i * 16 + rb + r][wave] = s;
        rs2[i * 16 + rb + r][wave] = s2;
      }
    }
  __syncthreads();
  float mrow[4][4], rrow[4][4];
#pragma unroll
  for (int i = 0; i < 4; ++i)
#pragma unroll
    for (int r = 0; r < 4; ++r) {
      const int lr = i * 16 + rb + r;
      float4 s4 = *(const float4*)rs[lr];
      float4 q4 = *(const float4*)rs2[lr];
      float tot = s4.x + s4.y + s4.z + s4.w;
      float tot2 = q4.x + q4.y + q4.z + q4.w;
      float m = tot * (1.0f / 256.0f);
      float var = tot2 * (1.0f / 256.0f) - m * m;
      mrow[i][r] = m;
      rrow[i][r] = rsqrtf(var + LN_EPS_F);
    }
#pragma unroll
  for (int i = 0; i < 4; ++i)
#pragma unroll
    for (int j = 0; j < 4; ++j) {
      const int col = wave * 64 + j * 16 + l15;
      const float gv = g[col], bv = bb[col];
#pragma unroll
      for (int r = 0; r < 4; ++r) {
        const int row = bm + i * 16 + rb + r;
        float x = acc[i][j][r];
        Tout[(size_t)row * 256 + col] = x;
        Hout[(size_t)row * 256 + col] =
            __float2bfloat16((x - mrow[i][r]) * rrow[i][r] * gv + bv);
      }
    }
}

// ---------------- attention: MFMA, one wave per (window, head) --------------
__global__ __launch_bounds__(256) void attn_k(const ushort* __restrict__ qkv,
                                              __hip_bfloat16* __restrict__ o,
                                              float* __restrict__ attns_out,
                                              const float* __restrict__ bias_tbl,
                                              const float* __restrict__ sita_l) {
  __shared__ ushort smem[4 * 7424];
  __shared__ float tbl[225];
  const int tid = threadIdx.x;
  const int lane = tid & 63, wave = tid >> 6;
  const int head = blockIdx.x & 7;
  const int w = ((blockIdx.x >> 3) << 2) + wave;
  ushort* qw = smem + wave * 7424;
  ushort* kw = qw + 2560;
  ushort* vw = kw + 2560;
  ushort* Pw = qw;

  const float sita = sita_l[head];
  const float factor = 1.0f / (2.0f * sita * sita + 1e-10f);
  for (int idx = tid; idx < 225; idx += 256) {
    int dyi = idx / 15 - 7, dxi = idx % 15 - 7;
    float dis = (float)(dyi * dyi + dxi * dxi) * 0.015625f;
    tbl[idx] = bias_tbl[idx * NHEADS + head] + 0.01f * __expf(-factor * dis);
  }

  {
    const ushort* base = qkv + (size_t)(w * 64) * QKV_N + head * 32;
    const int r0 = lane >> 2, c = (lane & 3) << 3;
#pragma unroll
    for (int r4 = 0; r4 < 4; ++r4) {
      const int row = r4 * 16 + r0;
      const ushort* rp = base + (size_t)row * QKV_N + c;
      *(uint4*)(qw + row * 40 + c) = *(const uint4*)(rp);
      *(uint4*)(kw + row * 40 + c) = *(const uint4*)(rp + 256);
      union { uint4 u; ushort s[8]; } V;
      V.u = *(const uint4*)(rp + 512);
#pragma unroll
      for (int z = 0; z < 8; ++z) vw[(c + z) * 72 + row] = V.s[z];
    }
  }
  __syncthreads();

  const int l15 = lane & 15, quad = lane >> 4;

  f32x4 acc[4][4] = {};
  {
    bf16x8 af[4], bfr[4];
#pragma unroll
    for (int i = 0; i < 4; ++i)
      af[i] = *(const bf16x8*)(qw + (i * 16 + l15) * 40 + quad * 8);
#pragma unroll
    for (int j = 0; j < 4; ++j)
      bfr[j] = *(const bf16x8*)(kw + (j * 16 + l15) * 40 + quad * 8);
#pragma unroll
    for (int i = 0; i < 4; ++i)
#pragma unroll
      for (int j = 0; j < 4; ++j)
        acc[i][j] =
            __builtin_amdgcn_mfma_f32_16x16x32_bf16(af[i], bfr[j], acc[i][j], 0, 0, 0);
  }

  float e1[4][4][4];
#pragma unroll
  for (int i = 0; i < 4; ++i)
#pragma unroll
    for (int r = 0; r < 4; ++r) {
      const int row = i * 16 + quad * 4 + r;
      const int iy = row >> 3, ix = row & 7;
#pragma unroll
      for (int j = 0; j < 4; ++j) {
        const int col = j * 16 + l15;
        const int jy = col >> 3, jx = col & 7;
        float d0 = acc[i][j][r] * SCALE_F;
        acc[i][j][r] = d0;
        e1[i][j][r] = d0 + tbl[(iy - jy + 7) * 15 + (ix - jx + 7)];
      }
    }

#pragma unroll
  for (int i = 0; i < 4; ++i)
#pragma unroll
    for (int r = 0; r < 4; ++r) {
      float m0 = -1e30f, m1 = -1e30f;
#pragma unroll
      for (int j = 0; j < 4; ++j) {
        m0 = fmaxf(m0, acc[i][j][r]);
        m1 = fmaxf(m1, e1[i][j][r]);
      }
      m0 = fmaxf(m0, __shfl_xor(m0, 1)); m0 = fmaxf(m0, __shfl_xor(m0, 2));
      m0 = fmaxf(m0, __shfl_xor(m0, 4)); m0 = fmaxf(m0, __shfl_xor(m0, 8));
      m1 = fmaxf(m1, __shfl_xor(m1, 1)); m1 = fmaxf(m1, __shfl_xor(m1, 2));
      m1 = fmaxf(m1, __shfl_xor(m1, 4)); m1 = fmaxf(m1, __shfl_xor(m1, 8));
      float z0 = 0.f, z1 = 0.f;
#pragma unroll
      for (int j = 0; j < 4; ++j) {
        float a = __expf(acc[i][j][r] - m0); acc[i][j][r] = a; z0 += a;
        float bqq = __expf(e1[i][j][r] - m1); e1[i][j][r] = bqq; z1 += bqq;
      }
      z0 += __shfl_xor(z0, 1); z0 += __shfl_xor(z0, 2);
      z0 += __shfl_xor(z0, 4); z0 += __shfl_xor(z0, 8);
      z1 += __shfl_xor(z1, 1); z1 += __shfl_xor(z1, 2);
      z1 += __shfl_xor(z1, 4); z1 += __shfl_xor(z1, 8);
      const float r0i = 1.f / z0, r1i = 1.f / z1;
#pragma unroll
      for (int j = 0; j < 4; ++j) {
        acc[i][j][r] *= r0i;
        e1[i][j][r] *= r1i;
      }
    }

  {
    float* ab = attns_out + ((size_t)(w * NHEADS + head)) * 4096;
#pragma unroll
    for (int i = 0; i < 4; ++i)
#pragma unroll
      for (int j = 0; j < 4; ++j)
#pragma unroll
        for (int r = 0; r < 4; ++r)
          ab[(i * 16 + quad * 4 + r) * 64 + j * 16 + l15] = acc[i][j][r];
  }

#pragma unroll
  for (int i = 0; i < 4; ++i)
#pragma unroll
    for (int j = 0; j < 4; ++j)
#pragma unroll
      for (int r = 0; r < 4; ++r)
        Pw[(i * 16 + quad * 4 + r) * 72 + j * 16 + l15] =
            ((__hip_bfloat16_raw)__float2bfloat16(e1[i][j][r])).x;

  f32x4 oacc[4][2] = {};
#pragma unroll
  for (int ks = 0; ks < 2; ++ks) {
    bf16x8 pa[4], vb[2];
#pragma unroll
    for (int i = 0; i < 4; ++i)
      pa[i] = *(const bf16x8*)(Pw + (i * 16 + l15) * 72 + ks * 32 + quad * 8);
#pragma unroll
    for (int j = 0; j < 2; ++j)
      vb[j] = *(const bf16x8*)(vw + (j * 16 + l15) * 72 + ks * 32 + quad * 8);
#pragma unroll
    for (int i = 0; i < 4; ++i)
#pragma unroll
      for (int j = 0; j < 2; ++j)
        oacc[i][j] =
            __builtin_amdgcn_mfma_f32_16x16x32_bf16(pa[i], vb[j], oacc[i][j], 0, 0, 0);
  }
  {
    ushort* ob = (ushort*)o + (size_t)(w * 64) * DMODEL + head * 32;
#pragma unroll
    for (int i = 0; i < 4; ++i)
#pragma unroll
      for (int j = 0; j < 2; ++j)
#pragma unroll
        for (int r = 0; r < 4; ++r)
          ob[(size_t)(i * 16 + quad * 4 + r) * DMODEL + j * 16 + l15] =
              ((__hip_bfloat16_raw)__float2bfloat16(oacc[i][j][r])).x;
  }
}

// ---------------------------------------------------------------------------
extern "C" void kernel_launch(void* const* d_in, const int* in_sizes, int n_in,
                              void* d_out, int out_size, void* d_ws, size_t ws_size,
                              hipStream_t stream) {
  const float* x        = (const float*)d_in[0];
  const float* W_patch  = (const float*)d_in[1];
  const float* b_patch  = (const float*)d_in[2];
  const float* ln1_g    = (const float*)d_in[3];
  const float* ln1_b    = (const float*)d_in[4];
  const float* Wqkv     = (const float*)d_in[5];
  const float* headsita = (const float*)d_in[6];
  const float* bias_tbl = (const float*)d_in[7];
  const float* Wout     = (const float*)d_in[8];
  const float* bout     = (const float*)d_in[9];
  const float* ln2_g    = (const float*)d_in[10];
  const float* ln2_b    = (const float*)d_in[11];
  const float* W1       = (const float*)d_in[12];
  const float* b1       = (const float*)d_in[13];
  const float* W2       = (const float*)d_in[14];
  const float* b2       = (const float*)d_in[15];

  char* W = (char*)d_ws;
  float*  t   = (float*)W;                       // [65536,256] f32, 64 MB
  ushort* h   = (ushort*)(W + 67108864);         // [65536,256] bf16, 32 MB
  ushort* qkv = (ushort*)(W + 100663296);        // [65536,768] bf16, 96 MB
  ushort* o   = (ushort*)(W + 201326592);        // [65536,256] bf16, 32 MB
  ushort* wT  = (ushort*)(W + 234881024);        // transposed bf16 weights
  ushort* Xg  = qkv;                             // overlap (dead before qkv GEMM)
  ushort* hid = qkv;                             // [65536,1024] bf16

  ushort* WpT   = wT;
  ushort* WqkvT = wT + 65536;
  ushort* WoutT = wT + 458752;
  ushort* W1T   = wT + 589824;
  ushort* W2T   = wT + 1114112;

  float* out_img = (float*)d_out;
  float* attns   = out_img + 16777216;

  transpose_all_k<<<1600, 256, 0, stream>>>(
      W_patch, Wqkv, Wout, W1, W2, WpT, WqkvT, WoutT, W1T, W2T);

  gather_k<<<2048, 256, 0, stream>>>(x, Xg);
  // patch embed + fused LN1 (layer 0)
  mm_ln_k<false><<<1024, 256, 0, stream>>>(
      Xg, WpT, b_patch, nullptr, t, (__hip_bfloat16*)h, ln1_g, ln1_b, 256);

  for (int l = 0; l < 2; ++l) {
    mm_k<false, false, false, true><<<dim3(512, 6), 256, 0, stream>>>(
        h, WqkvT + (size_t)l * 196608, nullptr, nullptr, qkv, ROWS, QKV_N, DMODEL);
    attn_k<<<2048, 256, 0, stream>>>(
        qkv, (__hip_bfloat16*)o, attns + (size_t)l * 33554432,
        bias_tbl + l * 225 * NHEADS, headsita + l * NHEADS);
    // out-proj + residual + fused LN2
    mm_ln_k<true><<<1024, 256, 0, stream>>>(
        o, WoutT + (size_t)l * 65536, bout + l * 256, t, t, (__hip_bfloat16*)h,
        ln2_g + l * 256, ln2_b + l * 256, 256);
    mm_k<true, true, false, true><<<dim3(512, 8), 256, 0, stream>>>(
        h, W1T + (size_t)l * 262144, b1 + l * MLP_N, nullptr, hid, ROWS, MLP_N, DMODEL);
    if (l == 0) {
      // W2 + residual + fused LN1 of layer 1
      mm_ln_k<true><<<1024, 256, 0, stream>>>(
          hid, W2T, b2, t, t, (__hip_bfloat16*)h, ln1_g + 256, ln1_b + 256, 1024);
    } else {
      mm_k<true, false, true, false><<<dim3(512, 2), 256, 0, stream>>>(
          hid, W2T + 262144, b2 + 256, t, t, ROWS, DMODEL, MLP_N);
    }
  }

  unwindow_k<<<2048, 256, 0, stream>>>(t, out_img);
}

// Round 3
// 1057.240 us; speedup vs baseline: 1.3022x; 1.1033x over previous
//
#include <hip/hip_runtime.h>
#include <hip/hip_bf16.h>
#include <cstddef>
#include <cstdint>

// ---------------------------------------------------------------------------
// StandardPartitionAttention — round 4:
//  * QKV GEMM fused INTO attention: block = 1 window (512 thr, 8 waves = 8
//    heads). h staged once in LDS (xor-swizzled via pre-swizzled global src),
//    each wave computes q/k/v via MFMA (64x32x256, weights streamed from L2),
//    then the round-1-verified QK^T/softmax/AV math runs unchanged.
//    Deletes the K=256 qkv GEMM + 96 MB qkv buffer round-trip per layer.
//  * Everything else identical to round 3 (verified).
// ---------------------------------------------------------------------------

#define ROWS      65536
#define DMODEL    256
#define NWIN      1024
#define NHEADS    8
#define QKV_N     768
#define MLP_N     1024
#define SCALE_F   0.17677669529663687f
#define LN_EPS_F  1e-5f

typedef float f32x4 __attribute__((ext_vector_type(4)));
typedef __bf16 bf16x8 __attribute__((ext_vector_type(8)));

#define CP16(gp, lp)                                                          \
  __builtin_amdgcn_global_load_lds(                                           \
      (const __attribute__((address_space(1))) unsigned int*)(gp),            \
      (__attribute__((address_space(3))) unsigned int*)(lp), 16, 0, 0)

// ---------------- window gather: x[B,C,H,W] -> Xg[row, c] (bf16) ------------
__global__ __launch_bounds__(256) void gather_k(const float* __restrict__ x,
                                                ushort* __restrict__ Xg) {
  __shared__ float tile[64 * 132];   // [c'][xx], pad 132 (16B-aligned rows)
  const int tid = threadIdx.x;
  const int bid = blockIdx.x;
  const int chunk = bid & 3;
  const int y = (bid >> 2) & 127;
  const int b = bid >> 9;
  const int c0 = chunk << 6;
  {
    const int x4 = tid & 31, cr = tid >> 5;
#pragma unroll
    for (int p = 0; p < 8; ++p) {
      const int cl = cr + p * 8;
      const float4 v = *(const float4*)(x +
          ((((size_t)b * 256 + c0 + cl) * 128 + y) * 128 + x4 * 4));
      *(float4*)(tile + cl * 132 + x4 * 4) = v;
    }
  }
  __syncthreads();
  {
    const int xx = tid >> 1, half = tid & 1;
    union { ushort s[32]; uint4 q[4]; } U;
#pragma unroll
    for (int cp = 0; cp < 32; ++cp) {
      const float v = tile[(half * 32 + cp) * 132 + xx];
      U.s[cp] = ((__hip_bfloat16_raw)__float2bfloat16(v)).x;
    }
    const int row = ((b * 16 + (y >> 3)) * 16 + (xx >> 3)) * 64 +
                    (y & 7) * 8 + (xx & 7);
    uint4* dst = (uint4*)(Xg + (size_t)row * 256 + c0 + half * 32);
#pragma unroll
    for (int z = 0; z < 4; ++z) dst[z] = U.q[z];
  }
}

// ---------------- un-window: t[row, d] -> out[B,D,H,W] ----------------------
__global__ __launch_bounds__(256) void unwindow_k(const float* __restrict__ t,
                                                  float* __restrict__ out) {
  __shared__ float tile[128 * 65];   // [xx][d'], pad 65
  const int tid = threadIdx.x;
  const int bid = blockIdx.x;
  const int dchunk = bid & 3;
  const int y = (bid >> 2) & 127;
  const int b = bid >> 9;
  const int d0 = dchunk << 6;
  {
    const int d4 = tid & 15, xr = tid >> 4;
#pragma unroll
    for (int p = 0; p < 8; ++p) {
      const int xx = xr + p * 16;
      const int row = ((b * 16 + (y >> 3)) * 16 + (xx >> 3)) * 64 +
                      (y & 7) * 8 + (xx & 7);
      const float4 v = *(const float4*)(t + (size_t)row * 256 + d0 + d4 * 4);
      tile[xx * 65 + d4 * 4 + 0] = v.x;
      tile[xx * 65 + d4 * 4 + 1] = v.y;
      tile[xx * 65 + d4 * 4 + 2] = v.z;
      tile[xx * 65 + d4 * 4 + 3] = v.w;
    }
  }
  __syncthreads();
  {
    const int xx = tid & 127, dd = tid >> 7;
#pragma unroll
    for (int p = 0; p < 32; ++p) {
      const int d = p * 2 + dd;
      out[(((size_t)b * 256 + d0 + d) * 128 + y) * 128 + xx] =
          tile[xx * 65 + d];
    }
  }
}

// ---------------- all weight transposes in one launch -----------------------
__global__ __launch_bounds__(256) void transpose_all_k(
    const float* __restrict__ Wp, const float* __restrict__ Wqkv,
    const float* __restrict__ Wo, const float* __restrict__ W1,
    const float* __restrict__ W2, ushort* __restrict__ WpT,
    ushort* __restrict__ WqkvT, ushort* __restrict__ WoT,
    ushort* __restrict__ W1T, ushort* __restrict__ W2T) {
  __shared__ float tile[32][33];
  const int bid = blockIdx.x;
  const float* src; ushort* dst; int K, N, r;
  if (bid < 64) { src = Wp; dst = WpT; K = 256; N = 256; r = bid; }
  else {
    const int tt = bid - 64, l = tt / 768; r = tt % 768;
    if (r < 192)      { src = Wqkv + (size_t)l * 196608; dst = WqkvT + (size_t)l * 196608; K = 256; N = 768; }
    else if (r < 256) { src = Wo + (size_t)l * 65536;  dst = WoT + (size_t)l * 65536;  K = 256; N = 256;  r -= 192; }
    else if (r < 512) { src = W1 + (size_t)l * 262144; dst = W1T + (size_t)l * 262144; K = 256; N = 1024; r -= 256; }
    else              { src = W2 + (size_t)l * 262144; dst = W2T + (size_t)l * 262144; K = 1024; N = 256; r -= 512; }
  }
  const int nx = N >> 5;
  const int n0 = (r % nx) * 32, k0 = (r / nx) * 32;
  const int tx = threadIdx.x & 31, ty = threadIdx.x >> 5;
#pragma unroll
  for (int i = 0; i < 4; ++i)
    tile[ty + i * 8][tx] = src[(size_t)(k0 + ty + i * 8) * N + n0 + tx];
  __syncthreads();
#pragma unroll
  for (int i = 0; i < 4; ++i)
    dst[(size_t)(n0 + ty + i * 8) * K + k0 + tx] =
        ((__hip_bfloat16_raw)__float2bfloat16(tile[tx][ty + i * 8])).x;
}

// ---------------- bf16 MFMA GEMM, 128x128 tile, BK=64 -----------------------
template <bool BIAS, bool RELU, bool RES, bool OBF16>
__global__ __launch_bounds__(256) void mm_k(const ushort* __restrict__ A,
                                            const ushort* __restrict__ BT,
                                            const float* __restrict__ bias,
                                            const float* __restrict__ res,
                                            void* __restrict__ Cout,
                                            int M, int N, int K) {
  __shared__ ushort As[8192];
  __shared__ ushort Bs[8192];
  const int tid = threadIdx.x;
  const int bm = blockIdx.x << 7, bn = blockIdx.y << 7;
  const ushort* Ap = A + (size_t)(bm + (tid >> 2)) * K + ((tid & 3) << 3);
  const ushort* Bp = BT + (size_t)(bn + (tid >> 2)) * K + ((tid & 3) << 3);
  const size_t k64 = (size_t)64 * K;
  const int lane = tid & 63, wave = tid >> 6;
  const int wm = (wave & 1) << 6, wn = (wave >> 1) << 6;
  const int lrow = lane & 15, kq = lane >> 4;
  const ushort* aF = &As[(wm + lrow) * 32 + kq * 8];
  const ushort* bF = &Bs[(wn + lrow) * 32 + kq * 8];
  f32x4 acc[4][4] = {};
  for (int k0 = 0; k0 < K; k0 += 64) {
    __syncthreads();
    CP16(Ap, &As[tid * 8]);
    CP16(Ap + k64, &As[2048 + tid * 8]);
    CP16(Ap + 32, &As[4096 + tid * 8]);
    CP16(Ap + k64 + 32, &As[6144 + tid * 8]);
    CP16(Bp, &Bs[tid * 8]);
    CP16(Bp + k64, &Bs[2048 + tid * 8]);
    CP16(Bp + 32, &Bs[4096 + tid * 8]);
    CP16(Bp + k64 + 32, &Bs[6144 + tid * 8]);
    Ap += 64; Bp += 64;
    __syncthreads();
#pragma unroll
    for (int c = 0; c < 2; ++c) {
      bf16x8 af[4], bf[4];
#pragma unroll
      for (int i = 0; i < 4; ++i) af[i] = *(const bf16x8*)(aF + c * 4096 + i * 512);
#pragma unroll
      for (int j = 0; j < 4; ++j) bf[j] = *(const bf16x8*)(bF + c * 4096 + j * 512);
#pragma unroll
      for (int i = 0; i < 4; ++i)
#pragma unroll
        for (int j = 0; j < 4; ++j)
          acc[i][j] =
              __builtin_amdgcn_mfma_f32_16x16x32_bf16(af[i], bf[j], acc[i][j], 0, 0, 0);
    }
  }
  const int r0 = bm + wm + kq * 4;
  const int c0 = bn + wn + lrow;
#pragma unroll
  for (int i = 0; i < 4; ++i) {
#pragma unroll
    for (int j = 0; j < 4; ++j) {
      const int col = c0 + j * 16;
      const float bv = BIAS ? bias[col] : 0.f;
#pragma unroll
      for (int r = 0; r < 4; ++r) {
        const int row = r0 + i * 16 + r;
        float v = acc[i][j][r] + bv;
        if (RELU) v = fmaxf(v, 0.f);
        if (RES) v += res[(size_t)row * N + col];
        if (OBF16)
          ((__hip_bfloat16*)Cout)[(size_t)row * N + col] = __float2bfloat16(v);
        else
          ((float*)Cout)[(size_t)row * N + col] = v;
      }
    }
  }
}

// ---------------- GEMM (N=256, tile 64x256, BK=64) + fused LayerNorm --------
template <bool RES>
__global__ __launch_bounds__(256) void mm_ln_k(const ushort* __restrict__ A,
                                               const ushort* __restrict__ BT,
                                               const float* __restrict__ bias,
                                               const float* __restrict__ res,
                                               float* __restrict__ Tout,
                                               __hip_bfloat16* __restrict__ Hout,
                                               const float* __restrict__ g,
                                               const float* __restrict__ bb,
                                               int K) {
  __shared__ ushort As[4096];       // [2][64][32]
  __shared__ ushort Bs[16384];      // [2][256][32]
  __shared__ float rs[64][4], rs2[64][4];
  const int tid = threadIdx.x;
  const int bm = blockIdx.x << 6;
  const ushort* Ap = A + (size_t)(bm + (tid >> 2)) * K + ((tid & 3) << 3);
  const ushort* Bp = BT + (size_t)(tid >> 2) * K + ((tid & 3) << 3);
  const size_t k64 = (size_t)64 * K;
  const int lane = tid & 63, wave = tid >> 6;
  const int l15 = lane & 15, quad = lane >> 4;
  const ushort* aF = &As[l15 * 32 + quad * 8];
  const ushort* bF = &Bs[(wave * 64 + l15) * 32 + quad * 8];
  f32x4 acc[4][4] = {};
  for (int k0 = 0; k0 < K; k0 += 64) {
    __syncthreads();
    CP16(Ap, &As[tid * 8]);
    CP16(Ap + 32, &As[2048 + tid * 8]);
#pragma unroll
    for (int cb = 0; cb < 4; ++cb) {
      CP16(Bp + cb * k64, &Bs[cb * 2048 + tid * 8]);
      CP16(Bp + cb * k64 + 32, &Bs[8192 + cb * 2048 + tid * 8]);
    }
    Ap += 64; Bp += 64;
    __syncthreads();
#pragma unroll
    for (int c = 0; c < 2; ++c) {
      bf16x8 af[4], bf[4];
#pragma unroll
      for (int i = 0; i < 4; ++i) af[i] = *(const bf16x8*)(aF + c * 2048 + i * 512);
#pragma unroll
      for (int j = 0; j < 4; ++j) bf[j] = *(const bf16x8*)(bF + c * 8192 + j * 512);
#pragma unroll
      for (int i = 0; i < 4; ++i)
#pragma unroll
        for (int j = 0; j < 4; ++j)
          acc[i][j] =
              __builtin_amdgcn_mfma_f32_16x16x32_bf16(af[i], bf[j], acc[i][j], 0, 0, 0);
    }
  }
  // epilogue: bias (+res), then full-row LN across 256 cols
  const int rb = quad * 4;
#pragma unroll
  for (int i = 0; i < 4; ++i)
#pragma unroll
    for (int j = 0; j < 4; ++j) {
      const int col = wave * 64 + j * 16 + l15;
      const float bv = bias[col];
#pragma unroll
      for (int r = 0; r < 4; ++r) {
        const int row = bm + i * 16 + rb + r;
        float x = acc[i][j][r] + bv;
        if (RES) x += res[(size_t)row * 256 + col];
        acc[i][j][r] = x;
      }
    }
#pragma unroll
  for (int i = 0; i < 4; ++i)
#pragma unroll
    for (int r = 0; r < 4; ++r) {
      float s = 0.f, s2 = 0.f;
#pragma unroll
      for (int j = 0; j < 4; ++j) {
        float x = acc[i][j][r];
        s += x; s2 += x * x;
      }
      s += __shfl_xor(s, 1);  s += __shfl_xor(s, 2);
      s += __shfl_xor(s, 4);  s += __shfl_xor(s, 8);
      s2 += __shfl_xor(s2, 1); s2 += __shfl_xor(s2, 2);
      s2 += __shfl_xor(s2, 4); s2 += __shfl_xor(s2, 8);
      if (l15 == 0) {
        rs[i * 16 + rb + r][wave] = s;
        rs2[i * 16 + rb + r][wave] = s2;
      }
    }
  __syncthreads();
  float mrow[4][4], rrow[4][4];
#pragma unroll
  for (int i = 0; i < 4; ++i)
#pragma unroll
    for (int r = 0; r < 4; ++r) {
      const int lr = i * 16 + rb + r;
      float4 s4 = *(const float4*)rs[lr];
      float4 q4 = *(const float4*)rs2[lr];
      float tot = s4.x + s4.y + s4.z + s4.w;
      float tot2 = q4.x + q4.y + q4.z + q4.w;
      float m = tot * (1.0f / 256.0f);
      float var = tot2 * (1.0f / 256.0f) - m * m;
      mrow[i][r] = m;
      rrow[i][r] = rsqrtf(var + LN_EPS_F);
    }
#pragma unroll
  for (int i = 0; i < 4; ++i)
#pragma unroll
    for (int j = 0; j < 4; ++j) {
      const int col = wave * 64 + j * 16 + l15;
      const float gv = g[col], bv = bb[col];
#pragma unroll
      for (int r = 0; r < 4; ++r) {
        const int row = bm + i * 16 + rb + r;
        float x = acc[i][j][r];
        Tout[(size_t)row * 256 + col] = x;
        Hout[(size_t)row * 256 + col] =
            __float2bfloat16((x - mrow[i][r]) * rrow[i][r] * gv + bv);
      }
    }
}

// ---------------- fused QKV-gen + attention: block = 1 window ---------------
// 512 threads, 8 waves = 8 heads. h (LN1 out) staged once in LDS with xor
// swizzle; each wave computes q/k/v = h @ Wqkv_head via MFMA, then runs the
// proven QK^T / dual-softmax / AV sequence (wave-local, no barriers).
__global__ __launch_bounds__(512) void attn_fused_k(
    const ushort* __restrict__ h,       // [65536][256] bf16
    const ushort* __restrict__ WqkvT,   // [768][256] bf16
    __hip_bfloat16* __restrict__ o,
    float* __restrict__ attns_out,
    const float* __restrict__ bias_tbl,
    const float* __restrict__ sita_l) {
  __shared__ ushort hs[64 * 256];       // 32 KB, cols xor-swizzled by row
  __shared__ ushort smem[8 * 7424];     // 116 KB: per-wave q/k/vT/P
  __shared__ float tbl[8][225];         // 7.2 KB
  const int tid = threadIdx.x;
  const int lane = tid & 63, wave = tid >> 6;
  const int w = blockIdx.x;
  const int head = wave;
  ushort* qw = smem + wave * 7424;
  ushort* kw = qw + 2560;
  ushort* vw = kw + 2560;
  ushort* Pw = qw;                      // P (64x72) overlays q+k after QK^T

  // per-head bias+pos tables
  for (int idx = tid; idx < 8 * 225; idx += 512) {
    const int hh = idx / 225, e = idx - hh * 225;
    const float sita = sita_l[hh];
    const float factor = 1.0f / (2.0f * sita * sita + 1e-10f);
    const int dyi = e / 15 - 7, dxi = e % 15 - 7;
    const float dis = (float)(dyi * dyi + dxi * dxi) * 0.015625f;
    tbl[hh][e] = bias_tbl[e * NHEADS + hh] + 0.01f * __expf(-factor * dis);
  }

  // stage h window (64 rows x 512 B) -> LDS, source pre-swizzled so that
  // LDS[row][colB ^ ((row&7)<<4)] = h[row][colB]  (linear dest, rule 21)
  {
    const char* hb = (const char*)(h + (size_t)w * 64 * 256);
#pragma unroll
    for (int p = 0; p < 4; ++p) {
      const int off = p * 8192 + tid * 16;
      const int row = off >> 9;
      const int col = (off & 511) ^ ((row & 7) << 4);
      CP16(hb + row * 512 + col, (char*)hs + off);
    }
  }
  __syncthreads();

  const int l15 = lane & 15, quad = lane >> 4;

  // ---- q/k/v generation: three 64x32x256 GEMMs sharing A-frags ----
  {
    const ushort* Wq = WqkvT + (size_t)(head * 32) * 256;
    const ushort* Wk = WqkvT + (size_t)(256 + head * 32) * 256;
    const ushort* Wv = WqkvT + (size_t)(512 + head * 32) * 256;
    f32x4 qa[4][2] = {}, ka[4][2] = {}, va[4][2] = {};
#pragma unroll
    for (int k0 = 0; k0 < 256; k0 += 32) {
      bf16x8 af[4], bq[2], bk[2], bv[2];
#pragma unroll
      for (int i = 0; i < 4; ++i) {
        const int row = i * 16 + l15;
        const int cb = (k0 * 2 + quad * 16) ^ ((row & 7) << 4);
        af[i] = *(const bf16x8*)((const char*)hs + row * 512 + cb);
      }
#pragma unroll
      for (int j = 0; j < 2; ++j) {
        const int nro = (j * 16 + l15) * 256 + k0 + quad * 8;
        bq[j] = *(const bf16x8*)(Wq + nro);
        bk[j] = *(const bf16x8*)(Wk + nro);
        bv[j] = *(const bf16x8*)(Wv + nro);
      }
#pragma unroll
      for (int i = 0; i < 4; ++i)
#pragma unroll
        for (int j = 0; j < 2; ++j) {
          qa[i][j] = __builtin_amdgcn_mfma_f32_16x16x32_bf16(af[i], bq[j], qa[i][j], 0, 0, 0);
          ka[i][j] = __builtin_amdgcn_mfma_f32_16x16x32_bf16(af[i], bk[j], ka[i][j], 0, 0, 0);
          va[i][j] = __builtin_amdgcn_mfma_f32_16x16x32_bf16(af[i], bv[j], va[i][j], 0, 0, 0);
        }
    }
    // C-layout (row = i*16+quad*4+r, col = j*16+l15) -> LDS
#pragma unroll
    for (int i = 0; i < 4; ++i)
#pragma unroll
      for (int j = 0; j < 2; ++j)
#pragma unroll
        for (int r = 0; r < 4; ++r) {
          const int row = i * 16 + quad * 4 + r;
          const int col = j * 16 + l15;
          qw[row * 40 + col] = ((__hip_bfloat16_raw)__float2bfloat16(qa[i][j][r])).x;
          kw[row * 40 + col] = ((__hip_bfloat16_raw)__float2bfloat16(ka[i][j][r])).x;
          vw[col * 72 + row] = ((__hip_bfloat16_raw)__float2bfloat16(va[i][j][r])).x;
        }
  }
  // same-wave LDS write->read: compiler inserts lgkmcnt; no barrier needed.

  // ---- QK^T: 16 MFMA ----
  f32x4 acc[4][4] = {};
  {
    bf16x8 af[4], bfr[4];
#pragma unroll
    for (int i = 0; i < 4; ++i)
      af[i] = *(const bf16x8*)(qw + (i * 16 + l15) * 40 + quad * 8);
#pragma unroll
    for (int j = 0; j < 4; ++j)
      bfr[j] = *(const bf16x8*)(kw + (j * 16 + l15) * 40 + quad * 8);
#pragma unroll
    for (int i = 0; i < 4; ++i)
#pragma unroll
      for (int j = 0; j < 4; ++j)
        acc[i][j] =
            __builtin_amdgcn_mfma_f32_16x16x32_bf16(af[i], bfr[j], acc[i][j], 0, 0, 0);
  }

  // scores
  float e1[4][4][4];
#pragma unroll
  for (int i = 0; i < 4; ++i)
#pragma unroll
    for (int r = 0; r < 4; ++r) {
      const int row = i * 16 + quad * 4 + r;
      const int iy = row >> 3, ix = row & 7;
#pragma unroll
      for (int j = 0; j < 4; ++j) {
        const int col = j * 16 + l15;
        const int jy = col >> 3, jx = col & 7;
        float d0 = acc[i][j][r] * SCALE_F;
        acc[i][j][r] = d0;
        e1[i][j][r] = d0 + tbl[head][(iy - jy + 7) * 15 + (ix - jx + 7)];
      }
    }

  // dual softmax per row
#pragma unroll
  for (int i = 0; i < 4; ++i)
#pragma unroll
    for (int r = 0; r < 4; ++r) {
      float m0 = -1e30f, m1 = -1e30f;
#pragma unroll
      for (int j = 0; j < 4; ++j) {
        m0 = fmaxf(m0, acc[i][j][r]);
        m1 = fmaxf(m1, e1[i][j][r]);
      }
      m0 = fmaxf(m0, __shfl_xor(m0, 1)); m0 = fmaxf(m0, __shfl_xor(m0, 2));
      m0 = fmaxf(m0, __shfl_xor(m0, 4)); m0 = fmaxf(m0, __shfl_xor(m0, 8));
      m1 = fmaxf(m1, __shfl_xor(m1, 1)); m1 = fmaxf(m1, __shfl_xor(m1, 2));
      m1 = fmaxf(m1, __shfl_xor(m1, 4)); m1 = fmaxf(m1, __shfl_xor(m1, 8));
      float z0 = 0.f, z1 = 0.f;
#pragma unroll
      for (int j = 0; j < 4; ++j) {
        float a = __expf(acc[i][j][r] - m0); acc[i][j][r] = a; z0 += a;
        float bqq = __expf(e1[i][j][r] - m1); e1[i][j][r] = bqq; z1 += bqq;
      }
      z0 += __shfl_xor(z0, 1); z0 += __shfl_xor(z0, 2);
      z0 += __shfl_xor(z0, 4); z0 += __shfl_xor(z0, 8);
      z1 += __shfl_xor(z1, 1); z1 += __shfl_xor(z1, 2);
      z1 += __shfl_xor(z1, 4); z1 += __shfl_xor(z1, 8);
      const float r0i = 1.f / z0, r1i = 1.f / z1;
#pragma unroll
      for (int j = 0; j < 4; ++j) {
        acc[i][j][r] *= r0i;
        e1[i][j][r] *= r1i;
      }
    }

  // attns (softmax of dots0) -> d_out
  {
    float* ab = attns_out + ((size_t)(w * NHEADS + head)) * 4096;
#pragma unroll
    for (int i = 0; i < 4; ++i)
#pragma unroll
      for (int j = 0; j < 4; ++j)
#pragma unroll
        for (int r = 0; r < 4; ++r)
          ab[(i * 16 + quad * 4 + r) * 64 + j * 16 + l15] = acc[i][j][r];
  }

  // P -> LDS row-major bf16
#pragma unroll
  for (int i = 0; i < 4; ++i)
#pragma unroll
    for (int j = 0; j < 4; ++j)
#pragma unroll
      for (int r = 0; r < 4; ++r)
        Pw[(i * 16 + quad * 4 + r) * 72 + j * 16 + l15] =
            ((__hip_bfloat16_raw)__float2bfloat16(e1[i][j][r])).x;

  // AV: O = P @ V
  f32x4 oacc[4][2] = {};
#pragma unroll
  for (int ks = 0; ks < 2; ++ks) {
    bf16x8 pa[4], vb[2];
#pragma unroll
    for (int i = 0; i < 4; ++i)
      pa[i] = *(const bf16x8*)(Pw + (i * 16 + l15) * 72 + ks * 32 + quad * 8);
#pragma unroll
    for (int j = 0; j < 2; ++j)
      vb[j] = *(const bf16x8*)(vw + (j * 16 + l15) * 72 + ks * 32 + quad * 8);
#pragma unroll
    for (int i = 0; i < 4; ++i)
#pragma unroll
      for (int j = 0; j < 2; ++j)
        oacc[i][j] =
            __builtin_amdgcn_mfma_f32_16x16x32_bf16(pa[i], vb[j], oacc[i][j], 0, 0, 0);
  }
  {
    ushort* ob = (ushort*)o + (size_t)(w * 64) * DMODEL + head * 32;
#pragma unroll
    for (int i = 0; i < 4; ++i)
#pragma unroll
      for (int j = 0; j < 2; ++j)
#pragma unroll
        for (int r = 0; r < 4; ++r)
          ob[(size_t)(i * 16 + quad * 4 + r) * DMODEL + j * 16 + l15] =
              ((__hip_bfloat16_raw)__float2bfloat16(oacc[i][j][r])).x;
  }
}

// ---------------------------------------------------------------------------
extern "C" void kernel_launch(void* const* d_in, const int* in_sizes, int n_in,
                              void* d_out, int out_size, void* d_ws, size_t ws_size,
                              hipStream_t stream) {
  const float* x        = (const float*)d_in[0];
  const float* W_patch  = (const float*)d_in[1];
  const float* b_patch  = (const float*)d_in[2];
  const float* ln1_g    = (const float*)d_in[3];
  const float* ln1_b    = (const float*)d_in[4];
  const float* Wqkv     = (const float*)d_in[5];
  const float* headsita = (const float*)d_in[6];
  const float* bias_tbl = (const float*)d_in[7];
  const float* Wout     = (const float*)d_in[8];
  const float* bout     = (const float*)d_in[9];
  const float* ln2_g    = (const float*)d_in[10];
  const float* ln2_b    = (const float*)d_in[11];
  const float* W1       = (const float*)d_in[12];
  const float* b1       = (const float*)d_in[13];
  const float* W2       = (const float*)d_in[14];
  const float* b2       = (const float*)d_in[15];

  char* W = (char*)d_ws;
  float*  t   = (float*)W;                       // [65536,256] f32, 64 MB
  ushort* h   = (ushort*)(W + 67108864);         // [65536,256] bf16, 32 MB
  ushort* qkv = (ushort*)(W + 100663296);        // region reused as Xg / hid
  ushort* o   = (ushort*)(W + 201326592);        // [65536,256] bf16, 32 MB
  ushort* wT  = (ushort*)(W + 234881024);        // transposed bf16 weights
  ushort* Xg  = qkv;                             // dead before MLP uses hid
  ushort* hid = qkv;                             // [65536,1024] bf16

  ushort* WpT   = wT;
  ushort* WqkvT = wT + 65536;
  ushort* WoutT = wT + 458752;
  ushort* W1T   = wT + 589824;
  ushort* W2T   = wT + 1114112;

  float* out_img = (float*)d_out;
  float* attns   = out_img + 16777216;

  transpose_all_k<<<1600, 256, 0, stream>>>(
      W_patch, Wqkv, Wout, W1, W2, WpT, WqkvT, WoutT, W1T, W2T);

  gather_k<<<2048, 256, 0, stream>>>(x, Xg);
  // patch embed + fused LN1 (layer 0)
  mm_ln_k<false><<<1024, 256, 0, stream>>>(
      Xg, WpT, b_patch, nullptr, t, (__hip_bfloat16*)h, ln1_g, ln1_b, 256);

  for (int l = 0; l < 2; ++l) {
    attn_fused_k<<<1024, 512, 0, stream>>>(
        h, WqkvT + (size_t)l * 196608, (__hip_bfloat16*)o,
        attns + (size_t)l * 33554432,
        bias_tbl + l * 225 * NHEADS, headsita + l * NHEADS);
    // out-proj + residual + fused LN2
    mm_ln_k<true><<<1024, 256, 0, stream>>>(
        o, WoutT + (size_t)l * 65536, bout + l * 256, t, t, (__hip_bfloat16*)h,
        ln2_g + l * 256, ln2_b + l * 256, 256);
    mm_k<true, true, false, true><<<dim3(512, 8), 256, 0, stream>>>(
        h, W1T + (size_t)l * 262144, b1 + l * MLP_N, nullptr, hid, ROWS, MLP_N, DMODEL);
    if (l == 0) {
      // W2 + residual + fused LN1 of layer 1
      mm_ln_k<true><<<1024, 256, 0, stream>>>(
          hid, W2T, b2, t, t, (__hip_bfloat16*)h, ln1_g + 256, ln1_b + 256, 1024);
    } else {
      mm_k<true, false, true, false><<<dim3(512, 2), 256, 0, stream>>>(
          hid, W2T + 262144, b2 + 256, t, t, ROWS, DMODEL, MLP_N);
    }
  }

  unwindow_k<<<2048, 256, 0, stream>>>(t, out_img);
}